// Round 1
// baseline (12104.701 us; speedup 1.0000x reference)
//
#include <hip/hip_runtime.h>
#include <math.h>

#define NBASES 16
#define HID 64
#define FIL 64

// ShiftedSoftplus: softplus(x) - log(2), overflow-safe form.
__device__ __forceinline__ float sspf(float x) {
    return fmaxf(x, 0.f) + __logf(1.f + __expf(-fabsf(x))) - 0.69314718056f;
}

// ---------------- transpose mlp_w2 (per layer) so edge kernel reads rows of w2T ----------------
__global__ void k_transpose_w2(const float* __restrict__ w2, float* __restrict__ w2T) {
    int i = blockIdx.x * blockDim.x + threadIdx.x; // l*4096 + f*64 + j
    if (i >= 2 * 64 * 64) return;
    int l = i >> 12, r = i & 4095, f = r >> 6, j = r & 63;
    w2T[(l << 12) + (j << 6) + f] = w2[i];
}

// ---------------- edge geometry: d and cosine-cutoff C ----------------
__global__ void k_edge_geo(const float* __restrict__ pos, const float* __restrict__ shifts,
                           const int* __restrict__ ei, int E,
                           float* __restrict__ d_e, float* __restrict__ c_e) {
    int e = blockIdx.x * blockDim.x + threadIdx.x;
    if (e >= E) return;
    int s = ei[e], t = ei[E + e];
    float dx = pos[t * 3 + 0] - pos[s * 3 + 0] + shifts[e * 3 + 0];
    float dy = pos[t * 3 + 1] - pos[s * 3 + 1] + shifts[e * 3 + 1];
    float dz = pos[t * 3 + 2] - pos[s * 3 + 2] + shifts[e * 3 + 2];
    float d = sqrtf(dx * dx + dy * dy + dz * dz);
    d_e[e] = d;
    c_e[e] = 0.5f * (cosf(d * 0.6283185307179586f) + 1.0f); // pi/CUTOFF = pi/5
}

// ---------------- node embedding: h = node_attrs @ W_v^T ----------------
__global__ void k_embed(const float* __restrict__ attrs, const float* __restrict__ wv,
                        int N, float* __restrict__ h) {
    int n = blockIdx.x * blockDim.x + threadIdx.x;
    if (n >= N) return;
    float a[5];
#pragma unroll
    for (int s = 0; s < 5; s++) a[s] = attrs[n * 5 + s];
    float4* out = (float4*)(h + (size_t)n * HID);
#pragma unroll 4
    for (int c = 0; c < 16; c++) {
        float4 o;
        float* op = (float*)&o;
#pragma unroll
        for (int q = 0; q < 4; q++) {
            int f = c * 4 + q;
            float acc = 0.f;
#pragma unroll
            for (int s = 0; s < 5; s++) acc += a[s] * wv[f * 5 + s];
            op[q] = acc;
        }
        out[c] = o;
    }
}

// ---------------- xf = h @ lin1_w^T (no bias) ----------------
__global__ void k_lin1(const float* __restrict__ h, const float* __restrict__ w,
                       int N, float* __restrict__ xf) {
    int n = blockIdx.x * blockDim.x + threadIdx.x;
    if (n >= N) return;
    float hv[64];
    const float4* hr = (const float4*)(h + (size_t)n * HID);
#pragma unroll
    for (int c = 0; c < 16; c++) {
        float4 v = hr[c];
        hv[c * 4 + 0] = v.x; hv[c * 4 + 1] = v.y; hv[c * 4 + 2] = v.z; hv[c * 4 + 3] = v.w;
    }
    float4* out = (float4*)(xf + (size_t)n * FIL);
#pragma unroll 4
    for (int c = 0; c < 16; c++) {
        float4 o;
        float* op = (float*)&o;
#pragma unroll
        for (int q = 0; q < 4; q++) {
            int f = c * 4 + q;
            float acc = 0.f;
#pragma unroll
            for (int j = 0; j < 64; j++) acc += hv[j] * w[f * 64 + j];
            op[q] = acc;
        }
        out[c] = o;
    }
}

// ---------------- the hot kernel: per-edge filter MLP + gather + scatter-add ----------------
__global__ void __launch_bounds__(256) k_edge_msg(
    const float* __restrict__ d_e, const float* __restrict__ c_e,
    const int* __restrict__ ei, int E,
    const float* __restrict__ w1, const float* __restrict__ b1,
    const float* __restrict__ w2T, const float* __restrict__ b2,
    const float* __restrict__ xf, float* __restrict__ agg) {
    int e = blockIdx.x * blockDim.x + threadIdx.x;
    if (e >= E) return;
    float dv = d_e[e];
    float cv = c_e[e];
    int s = ei[e], t = ei[E + e];

    // gaussian radial basis: offsets linspace(0,5,16), coeff = -0.5/(1/3)^2 = -4.5
    float g[16];
#pragma unroll
    for (int b = 0; b < NBASES; b++) {
        float u = dv - (float)b * (5.0f / 15.0f);
        g[b] = __expf(-4.5f * u * u);
    }

    float acc[64];
#pragma unroll
    for (int f = 0; f < FIL; f++) acc[f] = b2[f];

#pragma unroll 4
    for (int j = 0; j < FIL; j++) {
        float tt = b1[j];
#pragma unroll
        for (int b = 0; b < NBASES; b++) tt += w1[j * NBASES + b] * g[b];
        float hid = sspf(tt);
        const float* w2r = w2T + j * FIL;
#pragma unroll
        for (int f = 0; f < FIL; f++) acc[f] += w2r[f] * hid;
    }

    // msg = xf[src] * W * C ; scatter into agg[dst]
    const float4* xr = (const float4*)(xf + (size_t)s * FIL);
    float* ar = agg + (size_t)t * FIL;
#pragma unroll
    for (int c = 0; c < 16; c++) {
        float4 v = xr[c];
        unsafeAtomicAdd(ar + c * 4 + 0, v.x * acc[c * 4 + 0] * cv);
        unsafeAtomicAdd(ar + c * 4 + 1, v.y * acc[c * 4 + 1] * cv);
        unsafeAtomicAdd(ar + c * 4 + 2, v.z * acc[c * 4 + 2] * cv);
        unsafeAtomicAdd(ar + c * 4 + 3, v.w * acc[c * 4 + 3] * cv);
    }
}

// ---------------- node update: h += lin( ssp( lin2(agg) ) ) ----------------
__global__ void k_node_update(const float* __restrict__ agg,
                              const float* __restrict__ lin2w, const float* __restrict__ lin2b,
                              const float* __restrict__ linw, const float* __restrict__ linb,
                              int N, float* __restrict__ h) {
    int n = blockIdx.x * blockDim.x + threadIdx.x;
    if (n >= N) return;
    float av[64];
    const float4* ar = (const float4*)(agg + (size_t)n * FIL);
#pragma unroll
    for (int c = 0; c < 16; c++) {
        float4 v = ar[c];
        av[c * 4 + 0] = v.x; av[c * 4 + 1] = v.y; av[c * 4 + 2] = v.z; av[c * 4 + 3] = v.w;
    }
    float tv[64];
#pragma unroll 2
    for (int f = 0; f < HID; f++) {
        float acc = lin2b[f];
#pragma unroll
        for (int j = 0; j < FIL; j++) acc += av[j] * lin2w[f * FIL + j];
        tv[f] = sspf(acc);
    }
    float4* hr = (float4*)(h + (size_t)n * HID);
#pragma unroll 2
    for (int c = 0; c < 16; c++) {
        float4 hvv = hr[c];
        float* hp = (float*)&hvv;
#pragma unroll
        for (int q = 0; q < 4; q++) {
            int f = c * 4 + q;
            float acc = linb[f];
#pragma unroll
            for (int j = 0; j < HID; j++) acc += tv[j] * linw[f * HID + j];
            hp[q] += acc;
        }
        hr[c] = hvv;
    }
}

// ---------------- readout MLP + scatter mean accumulation ----------------
__global__ void k_readout(const float* __restrict__ h, const int* __restrict__ batch,
                          const float* __restrict__ w1, const float* __restrict__ b1,
                          const float* __restrict__ w2, const float* __restrict__ b2,
                          int N, float* __restrict__ sums, float* __restrict__ counts) {
    int n = blockIdx.x * blockDim.x + threadIdx.x;
    if (n >= N) return;
    float hv[64];
    const float4* hr = (const float4*)(h + (size_t)n * HID);
#pragma unroll
    for (int c = 0; c < 16; c++) {
        float4 v = hr[c];
        hv[c * 4 + 0] = v.x; hv[c * 4 + 1] = v.y; hv[c * 4 + 2] = v.z; hv[c * 4 + 3] = v.w;
    }
    float o = b2[0];
#pragma unroll 2
    for (int j = 0; j < 32; j++) {
        float acc = b1[j];
#pragma unroll
        for (int k = 0; k < 64; k++) acc += hv[k] * w1[j * 64 + k];
        o += sspf(acc) * w2[j];
    }
    int b = batch[n];
    unsafeAtomicAdd(&sums[b], o);
    unsafeAtomicAdd(&counts[b], 1.0f);
}

__global__ void k_finalize(const float* __restrict__ sums, const float* __restrict__ counts,
                           int G, float* __restrict__ out) {
    int g = blockIdx.x * blockDim.x + threadIdx.x;
    if (g >= G) return;
    out[g] = sums[g] / fmaxf(counts[g], 1.0f);
}

extern "C" void kernel_launch(void* const* d_in, const int* in_sizes, int n_in,
                              void* d_out, int out_size, void* d_ws, size_t ws_size,
                              hipStream_t stream) {
    const float* pos    = (const float*)d_in[0];
    const float* shifts = (const float*)d_in[1];
    const float* attrs  = (const float*)d_in[2];
    const int*   batch  = (const int*)d_in[3];
    const int*   ei     = (const int*)d_in[4];
    const float* wv     = (const float*)d_in[5];
    const float* mlp_w1 = (const float*)d_in[6];
    const float* mlp_b1 = (const float*)d_in[7];
    const float* mlp_w2 = (const float*)d_in[8];
    const float* mlp_b2 = (const float*)d_in[9];
    const float* lin1w  = (const float*)d_in[10];
    const float* lin2w  = (const float*)d_in[11];
    const float* lin2b  = (const float*)d_in[12];
    const float* linw   = (const float*)d_in[13];
    const float* linb   = (const float*)d_in[14];
    const float* ow1    = (const float*)d_in[15];
    const float* ob1    = (const float*)d_in[16];
    const float* ow2    = (const float*)d_in[17];
    const float* ob2    = (const float*)d_in[18];

    const int N = in_sizes[0] / 3;       // 100000
    const int E = in_sizes[4] / 2;       // 1600000
    const int G = out_size;              // 1000

    char* w = (char*)d_ws;
    float* d_e  = (float*)w; w += (size_t)E * 4;
    float* c_e  = (float*)w; w += (size_t)E * 4;
    float* h    = (float*)w; w += (size_t)N * HID * 4;
    float* xf   = (float*)w; w += (size_t)N * FIL * 4;
    float* agg  = (float*)w; w += (size_t)N * FIL * 4;
    float* w2T  = (float*)w; w += (size_t)2 * 64 * 64 * 4;
    float* sums = (float*)w; w += (size_t)G * 4;
    float* cnts = (float*)w; w += (size_t)G * 4;

    const int B = 256;
    k_transpose_w2<<<(2 * 64 * 64 + B - 1) / B, B, 0, stream>>>(mlp_w2, w2T);
    k_edge_geo<<<(E + B - 1) / B, B, 0, stream>>>(pos, shifts, ei, E, d_e, c_e);
    k_embed<<<(N + B - 1) / B, B, 0, stream>>>(attrs, wv, N, h);

    for (int l = 0; l < 2; l++) {
        k_lin1<<<(N + B - 1) / B, B, 0, stream>>>(h, lin1w + l * 4096, N, xf);
        hipMemsetAsync(agg, 0, (size_t)N * FIL * 4, stream);
        k_edge_msg<<<(E + B - 1) / B, B, 0, stream>>>(
            d_e, c_e, ei, E,
            mlp_w1 + l * 64 * NBASES, mlp_b1 + l * 64,
            w2T + l * 4096, mlp_b2 + l * 64,
            xf, agg);
        k_node_update<<<(N + B - 1) / B, B, 0, stream>>>(
            agg, lin2w + l * 4096, lin2b + l * 64, linw + l * 4096, linb + l * 64, N, h);
    }

    hipMemsetAsync(sums, 0, (size_t)G * 4, stream);
    hipMemsetAsync(cnts, 0, (size_t)G * 4, stream);
    k_readout<<<(N + B - 1) / B, B, 0, stream>>>(h, batch, ow1, ob1, ow2, ob2, N, sums, cnts);
    k_finalize<<<(G + B - 1) / B, B, 0, stream>>>(sums, cnts, G, (float*)d_out);
}

// Round 2
// 2903.531 us; speedup vs baseline: 4.1690x; 4.1690x over previous
//
#include <hip/hip_runtime.h>
#include <math.h>

#define NBASES 16
#define HID 64
#define FIL 64

// ShiftedSoftplus: softplus(x) - log(2), overflow-safe form.
__device__ __forceinline__ float sspf(float x) {
    return fmaxf(x, 0.f) + __logf(1.f + __expf(-fabsf(x))) - 0.69314718056f;
}

// ---------------- transpose mlp_w2 (per layer) so edge kernel reads rows of w2T ----------------
__global__ void k_transpose_w2(const float* __restrict__ w2, float* __restrict__ w2T) {
    int i = blockIdx.x * blockDim.x + threadIdx.x; // l*4096 + f*64 + j
    if (i >= 2 * 64 * 64) return;
    int l = i >> 12, r = i & 4095, f = r >> 6, j = r & 63;
    w2T[(l << 12) + (j << 6) + f] = w2[i];
}

// ---------------- CSR build: histogram of dst ----------------
__global__ void k_count(const int* __restrict__ ei, int E, int* __restrict__ cnt) {
    int e = blockIdx.x * blockDim.x + threadIdx.x;
    if (e >= E) return;
    atomicAdd(&cnt[ei[E + e]], 1);
}

// single-block exclusive scan over cnt[0..N) -> row_start[0..N], also copies to cursor
__global__ void k_scan(const int* __restrict__ cnt, int N,
                       int* __restrict__ row_start, int* __restrict__ cursor) {
    __shared__ int s[1024];
    int tid = threadIdx.x;
    int carry = 0;
    int nch = (N + 1023) / 1024;
    for (int c = 0; c < nch; c++) {
        int idx = c * 1024 + tid;
        int v = (idx < N) ? cnt[idx] : 0;
        s[tid] = v;
        __syncthreads();
        for (int off = 1; off < 1024; off <<= 1) {
            int t = (tid >= off) ? s[tid - off] : 0;
            __syncthreads();
            s[tid] += t;
            __syncthreads();
        }
        int incl = s[tid];
        if (idx < N) {
            int ex = carry + incl - v;
            row_start[idx] = ex;
            cursor[idx] = ex;
        }
        int tot = s[1023];
        __syncthreads();
        carry += tot;
    }
    if (tid == 0) row_start[N] = carry;
}

// fill CSR slots: fused edge geometry (d, cosine cutoff) + scatter to sorted position
__global__ void k_fill(const float* __restrict__ pos, const float* __restrict__ shifts,
                       const int* __restrict__ ei, int E, int* __restrict__ cursor,
                       int* __restrict__ src_s, float* __restrict__ d_s, float* __restrict__ c_s) {
    int e = blockIdx.x * blockDim.x + threadIdx.x;
    if (e >= E) return;
    int s = ei[e], t = ei[E + e];
    float dx = pos[t * 3 + 0] - pos[s * 3 + 0] + shifts[e * 3 + 0];
    float dy = pos[t * 3 + 1] - pos[s * 3 + 1] + shifts[e * 3 + 1];
    float dz = pos[t * 3 + 2] - pos[s * 3 + 2] + shifts[e * 3 + 2];
    float d = sqrtf(dx * dx + dy * dy + dz * dz);
    float C = 0.5f * (cosf(d * 0.6283185307179586f) + 1.0f); // pi/CUTOFF = pi/5
    int p = atomicAdd(&cursor[t], 1);
    src_s[p] = s;
    d_s[p] = d;
    c_s[p] = C;
}

// ---------------- node embedding: h = node_attrs @ W_v^T ----------------
__global__ void k_embed(const float* __restrict__ attrs, const float* __restrict__ wv,
                        int N, float* __restrict__ h) {
    int n = blockIdx.x * blockDim.x + threadIdx.x;
    if (n >= N) return;
    float a[5];
#pragma unroll
    for (int s = 0; s < 5; s++) a[s] = attrs[n * 5 + s];
    float4* out = (float4*)(h + (size_t)n * HID);
#pragma unroll 4
    for (int c = 0; c < 16; c++) {
        float4 o;
        float* op = (float*)&o;
#pragma unroll
        for (int q = 0; q < 4; q++) {
            int f = c * 4 + q;
            float acc = 0.f;
#pragma unroll
            for (int s = 0; s < 5; s++) acc += a[s] * wv[f * 5 + s];
            op[q] = acc;
        }
        out[c] = o;
    }
}

// ---------------- xf = h @ lin1_w^T (no bias) ----------------
__global__ void k_lin1(const float* __restrict__ h, const float* __restrict__ w,
                       int N, float* __restrict__ xf) {
    int n = blockIdx.x * blockDim.x + threadIdx.x;
    if (n >= N) return;
    float hv[64];
    const float4* hr = (const float4*)(h + (size_t)n * HID);
#pragma unroll
    for (int c = 0; c < 16; c++) {
        float4 v = hr[c];
        hv[c * 4 + 0] = v.x; hv[c * 4 + 1] = v.y; hv[c * 4 + 2] = v.z; hv[c * 4 + 3] = v.w;
    }
    float4* out = (float4*)(xf + (size_t)n * FIL);
#pragma unroll 4
    for (int c = 0; c < 16; c++) {
        float4 o;
        float* op = (float*)&o;
#pragma unroll
        for (int q = 0; q < 4; q++) {
            int f = c * 4 + q;
            float acc = 0.f;
#pragma unroll
            for (int j = 0; j < 64; j++) acc += hv[j] * w[f * 64 + j];
            op[q] = acc;
        }
        out[c] = o;
    }
}

// ---------------- edge filter MLP, sorted order, contiguous streaming writes ----------------
__global__ void __launch_bounds__(256) k_edge_mlp(
    const float* __restrict__ d_s, const float* __restrict__ c_s,
    const int* __restrict__ src_s, int c0, int cntE,
    const float* __restrict__ w1, const float* __restrict__ b1,
    const float* __restrict__ w2T, const float* __restrict__ b2,
    const float* __restrict__ xf, float* __restrict__ msgbuf) {
    int i = blockIdx.x * blockDim.x + threadIdx.x;
    if (i >= cntE) return;
    int gi = c0 + i;
    float dv = d_s[gi];
    float cv = c_s[gi];
    int s = src_s[gi];

    float g[16];
#pragma unroll
    for (int b = 0; b < NBASES; b++) {
        float u = dv - (float)b * (5.0f / 15.0f);
        g[b] = __expf(-4.5f * u * u);
    }

    float acc[64];
#pragma unroll
    for (int f = 0; f < FIL; f++) acc[f] = b2[f];

#pragma unroll 4
    for (int j = 0; j < FIL; j++) {
        float tt = b1[j];
#pragma unroll
        for (int b = 0; b < NBASES; b++) tt += w1[j * NBASES + b] * g[b];
        float hid = sspf(tt);
        const float* w2r = w2T + j * FIL;
#pragma unroll
        for (int f = 0; f < FIL; f++) acc[f] += w2r[f] * hid;
    }

    const float4* xr = (const float4*)(xf + (size_t)s * FIL);
    float4* mr = (float4*)(msgbuf + (size_t)i * FIL);
#pragma unroll
    for (int c = 0; c < 16; c++) {
        float4 v = xr[c];
        float4 o;
        o.x = v.x * acc[c * 4 + 0] * cv;
        o.y = v.y * acc[c * 4 + 1] * cv;
        o.z = v.z * acc[c * 4 + 2] * cv;
        o.w = v.w * acc[c * 4 + 3] * cv;
        mr[c] = o;
    }
}

// ---------------- segment sum over sorted msg rows: wave per node, lane per filter ----------------
__global__ void k_segsum(const int* __restrict__ row_start, int N, int c0, int c1,
                         const float* __restrict__ msgbuf, float* __restrict__ agg) {
    int wid = (blockIdx.x * blockDim.x + threadIdx.x) >> 6;
    int lane = threadIdx.x & 63;
    if (wid >= N) return;
    int rs = row_start[wid], re = row_start[wid + 1];
    int lo = rs > c0 ? rs : c0;
    int hi = re < c1 ? re : c1;
    if (lo >= hi) return;
    float a = 0.f;
    for (int r = lo; r < hi; r++) a += msgbuf[(size_t)(r - c0) * FIL + lane];
    float* dst = agg + (size_t)wid * FIL + lane;
    if (rs >= c0 && re <= c1) *dst = a;
    else unsafeAtomicAdd(dst, a);
}

// ---------------- fallback (workspace too small): original atomic-scatter edge kernel ----------------
__global__ void k_edge_geo(const float* __restrict__ pos, const float* __restrict__ shifts,
                           const int* __restrict__ ei, int E,
                           float* __restrict__ d_e, float* __restrict__ c_e) {
    int e = blockIdx.x * blockDim.x + threadIdx.x;
    if (e >= E) return;
    int s = ei[e], t = ei[E + e];
    float dx = pos[t * 3 + 0] - pos[s * 3 + 0] + shifts[e * 3 + 0];
    float dy = pos[t * 3 + 1] - pos[s * 3 + 1] + shifts[e * 3 + 1];
    float dz = pos[t * 3 + 2] - pos[s * 3 + 2] + shifts[e * 3 + 2];
    float d = sqrtf(dx * dx + dy * dy + dz * dz);
    d_e[e] = d;
    c_e[e] = 0.5f * (cosf(d * 0.6283185307179586f) + 1.0f);
}

__global__ void __launch_bounds__(256) k_edge_msg_atomic(
    const float* __restrict__ d_e, const float* __restrict__ c_e,
    const int* __restrict__ ei, int E,
    const float* __restrict__ w1, const float* __restrict__ b1,
    const float* __restrict__ w2T, const float* __restrict__ b2,
    const float* __restrict__ xf, float* __restrict__ agg) {
    int e = blockIdx.x * blockDim.x + threadIdx.x;
    if (e >= E) return;
    float dv = d_e[e];
    float cv = c_e[e];
    int s = ei[e], t = ei[E + e];
    float g[16];
#pragma unroll
    for (int b = 0; b < NBASES; b++) {
        float u = dv - (float)b * (5.0f / 15.0f);
        g[b] = __expf(-4.5f * u * u);
    }
    float acc[64];
#pragma unroll
    for (int f = 0; f < FIL; f++) acc[f] = b2[f];
#pragma unroll 4
    for (int j = 0; j < FIL; j++) {
        float tt = b1[j];
#pragma unroll
        for (int b = 0; b < NBASES; b++) tt += w1[j * NBASES + b] * g[b];
        float hid = sspf(tt);
        const float* w2r = w2T + j * FIL;
#pragma unroll
        for (int f = 0; f < FIL; f++) acc[f] += w2r[f] * hid;
    }
    const float4* xr = (const float4*)(xf + (size_t)s * FIL);
    float* ar = agg + (size_t)t * FIL;
#pragma unroll
    for (int c = 0; c < 16; c++) {
        float4 v = xr[c];
        unsafeAtomicAdd(ar + c * 4 + 0, v.x * acc[c * 4 + 0] * cv);
        unsafeAtomicAdd(ar + c * 4 + 1, v.y * acc[c * 4 + 1] * cv);
        unsafeAtomicAdd(ar + c * 4 + 2, v.z * acc[c * 4 + 2] * cv);
        unsafeAtomicAdd(ar + c * 4 + 3, v.w * acc[c * 4 + 3] * cv);
    }
}

// ---------------- node update: h += lin( ssp( lin2(agg) ) ) ----------------
__global__ void k_node_update(const float* __restrict__ agg,
                              const float* __restrict__ lin2w, const float* __restrict__ lin2b,
                              const float* __restrict__ linw, const float* __restrict__ linb,
                              int N, float* __restrict__ h) {
    int n = blockIdx.x * blockDim.x + threadIdx.x;
    if (n >= N) return;
    float av[64];
    const float4* ar = (const float4*)(agg + (size_t)n * FIL);
#pragma unroll
    for (int c = 0; c < 16; c++) {
        float4 v = ar[c];
        av[c * 4 + 0] = v.x; av[c * 4 + 1] = v.y; av[c * 4 + 2] = v.z; av[c * 4 + 3] = v.w;
    }
    float tv[64];
#pragma unroll 2
    for (int f = 0; f < HID; f++) {
        float acc = lin2b[f];
#pragma unroll
        for (int j = 0; j < FIL; j++) acc += av[j] * lin2w[f * FIL + j];
        tv[f] = sspf(acc);
    }
    float4* hr = (float4*)(h + (size_t)n * HID);
#pragma unroll 2
    for (int c = 0; c < 16; c++) {
        float4 hvv = hr[c];
        float* hp = (float*)&hvv;
#pragma unroll
        for (int q = 0; q < 4; q++) {
            int f = c * 4 + q;
            float acc = linb[f];
#pragma unroll
            for (int j = 0; j < HID; j++) acc += tv[j] * linw[f * HID + j];
            hp[q] += acc;
        }
        hr[c] = hvv;
    }
}

// ---------------- readout MLP + scatter mean accumulation ----------------
__global__ void k_readout(const float* __restrict__ h, const int* __restrict__ batch,
                          const float* __restrict__ w1, const float* __restrict__ b1,
                          const float* __restrict__ w2, const float* __restrict__ b2,
                          int N, float* __restrict__ sums, float* __restrict__ counts) {
    int n = blockIdx.x * blockDim.x + threadIdx.x;
    if (n >= N) return;
    float hv[64];
    const float4* hr = (const float4*)(h + (size_t)n * HID);
#pragma unroll
    for (int c = 0; c < 16; c++) {
        float4 v = hr[c];
        hv[c * 4 + 0] = v.x; hv[c * 4 + 1] = v.y; hv[c * 4 + 2] = v.z; hv[c * 4 + 3] = v.w;
    }
    float o = b2[0];
#pragma unroll 2
    for (int j = 0; j < 32; j++) {
        float acc = b1[j];
#pragma unroll
        for (int k = 0; k < 64; k++) acc += hv[k] * w1[j * 64 + k];
        o += sspf(acc) * w2[j];
    }
    int b = batch[n];
    unsafeAtomicAdd(&sums[b], o);
    unsafeAtomicAdd(&counts[b], 1.0f);
}

__global__ void k_finalize(const float* __restrict__ sums, const float* __restrict__ counts,
                           int G, float* __restrict__ out) {
    int g = blockIdx.x * blockDim.x + threadIdx.x;
    if (g >= G) return;
    out[g] = sums[g] / fmaxf(counts[g], 1.0f);
}

extern "C" void kernel_launch(void* const* d_in, const int* in_sizes, int n_in,
                              void* d_out, int out_size, void* d_ws, size_t ws_size,
                              hipStream_t stream) {
    const float* pos    = (const float*)d_in[0];
    const float* shifts = (const float*)d_in[1];
    const float* attrs  = (const float*)d_in[2];
    const int*   batch  = (const int*)d_in[3];
    const int*   ei     = (const int*)d_in[4];
    const float* wv     = (const float*)d_in[5];
    const float* mlp_w1 = (const float*)d_in[6];
    const float* mlp_b1 = (const float*)d_in[7];
    const float* mlp_w2 = (const float*)d_in[8];
    const float* mlp_b2 = (const float*)d_in[9];
    const float* lin1w  = (const float*)d_in[10];
    const float* lin2w  = (const float*)d_in[11];
    const float* lin2b  = (const float*)d_in[12];
    const float* linw   = (const float*)d_in[13];
    const float* linb   = (const float*)d_in[14];
    const float* ow1    = (const float*)d_in[15];
    const float* ob1    = (const float*)d_in[16];
    const float* ow2    = (const float*)d_in[17];
    const float* ob2    = (const float*)d_in[18];

    const int N = in_sizes[0] / 3;       // 100000
    const int E = in_sizes[4] / 2;       // 1600000
    const int G = out_size;              // 1000

    char* w = (char*)d_ws;
    size_t off = 0;
    auto alloc = [&](size_t bytes) -> char* {
        char* p = w + off;
        off = (off + bytes + 255) & ~(size_t)255;
        return p;
    };
    int*   cnt       = (int*)alloc((size_t)N * 4);
    int*   row_start = (int*)alloc((size_t)(N + 1) * 4);
    int*   cursor    = (int*)alloc((size_t)N * 4);
    int*   src_s     = (int*)alloc((size_t)E * 4);
    float* d_s       = (float*)alloc((size_t)E * 4);
    float* c_s       = (float*)alloc((size_t)E * 4);
    float* h         = (float*)alloc((size_t)N * HID * 4);
    float* xf        = (float*)alloc((size_t)N * FIL * 4);
    float* agg       = (float*)alloc((size_t)N * FIL * 4);
    float* w2T       = (float*)alloc((size_t)2 * 64 * 64 * 4);
    float* sums      = (float*)alloc((size_t)G * 4);
    float* cnts      = (float*)alloc((size_t)G * 4);
    size_t fixed = off;
    size_t avail = ws_size > fixed ? ws_size - fixed : 0;
    long long chunkE = (long long)(avail / (FIL * 4)) & ~63LL;
    if (chunkE > E) chunkE = E;
    bool chunked = chunkE >= 4096;
    float* msgbuf = (float*)(w + fixed);

    const int B = 256;
    k_transpose_w2<<<(2 * 64 * 64 + B - 1) / B, B, 0, stream>>>(mlp_w2, w2T);
    k_embed<<<(N + B - 1) / B, B, 0, stream>>>(attrs, wv, N, h);

    if (chunked) {
        hipMemsetAsync(cnt, 0, (size_t)N * 4, stream);
        k_count<<<(E + B - 1) / B, B, 0, stream>>>(ei, E, cnt);
        k_scan<<<1, 1024, 0, stream>>>(cnt, N, row_start, cursor);
        k_fill<<<(E + B - 1) / B, B, 0, stream>>>(pos, shifts, ei, E, cursor, src_s, d_s, c_s);

        for (int l = 0; l < 2; l++) {
            k_lin1<<<(N + B - 1) / B, B, 0, stream>>>(h, lin1w + l * 4096, N, xf);
            hipMemsetAsync(agg, 0, (size_t)N * FIL * 4, stream);
            for (long long c0 = 0; c0 < E; c0 += chunkE) {
                int cc = (int)((E - c0 < chunkE) ? (E - c0) : chunkE);
                k_edge_mlp<<<(cc + B - 1) / B, B, 0, stream>>>(
                    d_s, c_s, src_s, (int)c0, cc,
                    mlp_w1 + l * 64 * NBASES, mlp_b1 + l * 64,
                    w2T + l * 4096, mlp_b2 + l * 64, xf, msgbuf);
                k_segsum<<<((size_t)N * 64 + B - 1) / B, B, 0, stream>>>(
                    row_start, N, (int)c0, (int)(c0 + cc), msgbuf, agg);
            }
            k_node_update<<<(N + B - 1) / B, B, 0, stream>>>(
                agg, lin2w + l * 4096, lin2b + l * 64, linw + l * 4096, linb + l * 64, N, h);
        }
    } else {
        // fallback: original atomic-scatter path (reuses d_s/c_s as unsorted geo arrays)
        k_edge_geo<<<(E + B - 1) / B, B, 0, stream>>>(pos, shifts, ei, E, d_s, c_s);
        for (int l = 0; l < 2; l++) {
            k_lin1<<<(N + B - 1) / B, B, 0, stream>>>(h, lin1w + l * 4096, N, xf);
            hipMemsetAsync(agg, 0, (size_t)N * FIL * 4, stream);
            k_edge_msg_atomic<<<(E + B - 1) / B, B, 0, stream>>>(
                d_s, c_s, ei, E,
                mlp_w1 + l * 64 * NBASES, mlp_b1 + l * 64,
                w2T + l * 4096, mlp_b2 + l * 64, xf, agg);
            k_node_update<<<(N + B - 1) / B, B, 0, stream>>>(
                agg, lin2w + l * 4096, lin2b + l * 64, linw + l * 4096, linb + l * 64, N, h);
        }
    }

    hipMemsetAsync(sums, 0, (size_t)G * 4, stream);
    hipMemsetAsync(cnts, 0, (size_t)G * 4, stream);
    k_readout<<<(N + B - 1) / B, B, 0, stream>>>(h, batch, ow1, ob1, ow2, ob2, N, sums, cnts);
    k_finalize<<<(G + B - 1) / B, B, 0, stream>>>(sums, cnts, G, (float*)d_out);
}

// Round 3
// 2425.497 us; speedup vs baseline: 4.9906x; 1.1971x over previous
//
#include <hip/hip_runtime.h>
#include <math.h>

#define NBASES 16
#define HID 64
#define FIL 64

// ShiftedSoftplus: softplus(x) - log(2), overflow-safe form.
__device__ __forceinline__ float sspf(float x) {
    return fmaxf(x, 0.f) + __logf(1.f + __expf(-fabsf(x))) - 0.69314718056f;
}

// ---------------- transpose mlp_w2 (per layer) so edge kernel reads rows of w2T ----------------
__global__ void k_transpose_w2(const float* __restrict__ w2, float* __restrict__ w2T) {
    int i = blockIdx.x * blockDim.x + threadIdx.x; // l*4096 + f*64 + j
    if (i >= 2 * 64 * 64) return;
    int l = i >> 12, r = i & 4095, f = r >> 6, j = r & 63;
    w2T[(l << 12) + (j << 6) + f] = w2[i];
}

// ---------------- CSR build: histogram of dst ----------------
__global__ void k_count(const int* __restrict__ ei, int E, int* __restrict__ cnt) {
    int e = blockIdx.x * blockDim.x + threadIdx.x;
    if (e >= E) return;
    atomicAdd(&cnt[ei[E + e]], 1);
}

// single-block exclusive scan over cnt[0..N) -> row_start[0..N], also copies to cursor
__global__ void k_scan(const int* __restrict__ cnt, int N,
                       int* __restrict__ row_start, int* __restrict__ cursor) {
    __shared__ int s[1024];
    int tid = threadIdx.x;
    int carry = 0;
    int nch = (N + 1023) / 1024;
    for (int c = 0; c < nch; c++) {
        int idx = c * 1024 + tid;
        int v = (idx < N) ? cnt[idx] : 0;
        s[tid] = v;
        __syncthreads();
        for (int off = 1; off < 1024; off <<= 1) {
            int t = (tid >= off) ? s[tid - off] : 0;
            __syncthreads();
            s[tid] += t;
            __syncthreads();
        }
        int incl = s[tid];
        if (idx < N) {
            int ex = carry + incl - v;
            row_start[idx] = ex;
            cursor[idx] = ex;
        }
        int tot = s[1023];
        __syncthreads();
        carry += tot;
    }
    if (tid == 0) row_start[N] = carry;
}

// fill CSR slots: fused edge geometry (d, cosine cutoff) + scatter to sorted position
__global__ void k_fill(const float* __restrict__ pos, const float* __restrict__ shifts,
                       const int* __restrict__ ei, int E, int* __restrict__ cursor,
                       int* __restrict__ src_s, float* __restrict__ d_s, float* __restrict__ c_s) {
    int e = blockIdx.x * blockDim.x + threadIdx.x;
    if (e >= E) return;
    int s = ei[e], t = ei[E + e];
    float dx = pos[t * 3 + 0] - pos[s * 3 + 0] + shifts[e * 3 + 0];
    float dy = pos[t * 3 + 1] - pos[s * 3 + 1] + shifts[e * 3 + 1];
    float dz = pos[t * 3 + 2] - pos[s * 3 + 2] + shifts[e * 3 + 2];
    float d = sqrtf(dx * dx + dy * dy + dz * dz);
    float C = 0.5f * (cosf(d * 0.6283185307179586f) + 1.0f); // pi/CUTOFF = pi/5
    int p = atomicAdd(&cursor[t], 1);
    src_s[p] = s;
    d_s[p] = d;
    c_s[p] = C;
}

// ---------------- node embedding: h = node_attrs @ W_v^T ----------------
__global__ void k_embed(const float* __restrict__ attrs, const float* __restrict__ wv,
                        int N, float* __restrict__ h) {
    int n = blockIdx.x * blockDim.x + threadIdx.x;
    if (n >= N) return;
    float a[5];
#pragma unroll
    for (int s = 0; s < 5; s++) a[s] = attrs[n * 5 + s];
    float4* out = (float4*)(h + (size_t)n * HID);
#pragma unroll 4
    for (int c = 0; c < 16; c++) {
        float4 o;
        float* op = (float*)&o;
#pragma unroll
        for (int q = 0; q < 4; q++) {
            int f = c * 4 + q;
            float acc = 0.f;
#pragma unroll
            for (int s = 0; s < 5; s++) acc += a[s] * wv[f * 5 + s];
            op[q] = acc;
        }
        out[c] = o;
    }
}

// ---------------- xf = h @ lin1_w^T (no bias) ----------------
// __launch_bounds__(256,2): 256-VGPR budget so hv[64]+acc stay in registers (r2: spilled at 64 VGPR)
__global__ void __launch_bounds__(256, 2) k_lin1(
    const float* __restrict__ h, const float* __restrict__ w,
    int N, float* __restrict__ xf) {
    int n = blockIdx.x * blockDim.x + threadIdx.x;
    if (n >= N) return;
    float hv[64];
    const float4* hr = (const float4*)(h + (size_t)n * HID);
#pragma unroll
    for (int c = 0; c < 16; c++) {
        float4 v = hr[c];
        hv[c * 4 + 0] = v.x; hv[c * 4 + 1] = v.y; hv[c * 4 + 2] = v.z; hv[c * 4 + 3] = v.w;
    }
    float4* out = (float4*)(xf + (size_t)n * FIL);
#pragma unroll 4
    for (int c = 0; c < 16; c++) {
        float4 o;
        float* op = (float*)&o;
#pragma unroll
        for (int q = 0; q < 4; q++) {
            int f = c * 4 + q;
            float acc = 0.f;
#pragma unroll
            for (int j = 0; j < 64; j++) acc += hv[j] * w[f * 64 + j];
            op[q] = acc;
        }
        out[c] = o;
    }
}

// ---------------- edge filter MLP, sorted order, contiguous streaming writes ----------------
__global__ void __launch_bounds__(256, 2) k_edge_mlp(
    const float* __restrict__ d_s, const float* __restrict__ c_s,
    const int* __restrict__ src_s, int c0, int cntE,
    const float* __restrict__ w1, const float* __restrict__ b1,
    const float* __restrict__ w2T, const float* __restrict__ b2,
    const float* __restrict__ xf, float* __restrict__ msgbuf) {
    int i = blockIdx.x * blockDim.x + threadIdx.x;
    if (i >= cntE) return;
    int gi = c0 + i;
    float dv = d_s[gi];
    float cv = c_s[gi];
    int s = src_s[gi];

    float g[16];
#pragma unroll
    for (int b = 0; b < NBASES; b++) {
        float u = dv - (float)b * (5.0f / 15.0f);
        g[b] = __expf(-4.5f * u * u);
    }

    float acc[64];
#pragma unroll
    for (int f = 0; f < FIL; f++) acc[f] = b2[f];

#pragma unroll 4
    for (int j = 0; j < FIL; j++) {
        float tt = b1[j];
#pragma unroll
        for (int b = 0; b < NBASES; b++) tt += w1[j * NBASES + b] * g[b];
        float hid = sspf(tt);
        const float* w2r = w2T + j * FIL;
#pragma unroll
        for (int f = 0; f < FIL; f++) acc[f] += w2r[f] * hid;
    }

    const float4* xr = (const float4*)(xf + (size_t)s * FIL);
    float4* mr = (float4*)(msgbuf + (size_t)i * FIL);
#pragma unroll
    for (int c = 0; c < 16; c++) {
        float4 v = xr[c];
        float4 o;
        o.x = v.x * acc[c * 4 + 0] * cv;
        o.y = v.y * acc[c * 4 + 1] * cv;
        o.z = v.z * acc[c * 4 + 2] * cv;
        o.w = v.w * acc[c * 4 + 3] * cv;
        mr[c] = o;
    }
}

// ---------------- segment sum over sorted msg rows: wave per node, lane per filter ----------------
__global__ void k_segsum(const int* __restrict__ row_start, int N, int c0, int c1,
                         const float* __restrict__ msgbuf, float* __restrict__ agg) {
    int wid = (blockIdx.x * blockDim.x + threadIdx.x) >> 6;
    int lane = threadIdx.x & 63;
    if (wid >= N) return;
    int rs = row_start[wid], re = row_start[wid + 1];
    int lo = rs > c0 ? rs : c0;
    int hi = re < c1 ? re : c1;
    if (lo >= hi) return;
    float a = 0.f;
    for (int r = lo; r < hi; r++) a += msgbuf[(size_t)(r - c0) * FIL + lane];
    float* dst = agg + (size_t)wid * FIL + lane;
    if (rs >= c0 && re <= c1) *dst = a;
    else unsafeAtomicAdd(dst, a);
}

// ---------------- fallback (workspace too small): original atomic-scatter edge kernel ----------------
__global__ void k_edge_geo(const float* __restrict__ pos, const float* __restrict__ shifts,
                           const int* __restrict__ ei, int E,
                           float* __restrict__ d_e, float* __restrict__ c_e) {
    int e = blockIdx.x * blockDim.x + threadIdx.x;
    if (e >= E) return;
    int s = ei[e], t = ei[E + e];
    float dx = pos[t * 3 + 0] - pos[s * 3 + 0] + shifts[e * 3 + 0];
    float dy = pos[t * 3 + 1] - pos[s * 3 + 1] + shifts[e * 3 + 1];
    float dz = pos[t * 3 + 2] - pos[s * 3 + 2] + shifts[e * 3 + 2];
    float d = sqrtf(dx * dx + dy * dy + dz * dz);
    d_e[e] = d;
    c_e[e] = 0.5f * (cosf(d * 0.6283185307179586f) + 1.0f);
}

__global__ void __launch_bounds__(256, 2) k_edge_msg_atomic(
    const float* __restrict__ d_e, const float* __restrict__ c_e,
    const int* __restrict__ ei, int E,
    const float* __restrict__ w1, const float* __restrict__ b1,
    const float* __restrict__ w2T, const float* __restrict__ b2,
    const float* __restrict__ xf, float* __restrict__ agg) {
    int e = blockIdx.x * blockDim.x + threadIdx.x;
    if (e >= E) return;
    float dv = d_e[e];
    float cv = c_e[e];
    int s = ei[e], t = ei[E + e];
    float g[16];
#pragma unroll
    for (int b = 0; b < NBASES; b++) {
        float u = dv - (float)b * (5.0f / 15.0f);
        g[b] = __expf(-4.5f * u * u);
    }
    float acc[64];
#pragma unroll
    for (int f = 0; f < FIL; f++) acc[f] = b2[f];
#pragma unroll 4
    for (int j = 0; j < FIL; j++) {
        float tt = b1[j];
#pragma unroll
        for (int b = 0; b < NBASES; b++) tt += w1[j * NBASES + b] * g[b];
        float hid = sspf(tt);
        const float* w2r = w2T + j * FIL;
#pragma unroll
        for (int f = 0; f < FIL; f++) acc[f] += w2r[f] * hid;
    }
    const float4* xr = (const float4*)(xf + (size_t)s * FIL);
    float* ar = agg + (size_t)t * FIL;
#pragma unroll
    for (int c = 0; c < 16; c++) {
        float4 v = xr[c];
        unsafeAtomicAdd(ar + c * 4 + 0, v.x * acc[c * 4 + 0] * cv);
        unsafeAtomicAdd(ar + c * 4 + 1, v.y * acc[c * 4 + 1] * cv);
        unsafeAtomicAdd(ar + c * 4 + 2, v.z * acc[c * 4 + 2] * cv);
        unsafeAtomicAdd(ar + c * 4 + 3, v.w * acc[c * 4 + 3] * cv);
    }
}

// ---------------- node update: h += lin( ssp( lin2(agg) ) ) ----------------
// (256,2): av[64]+tv[64] = 128+ live floats; r2 showed 64-VGPR spill -> 649MB scratch fetch
__global__ void __launch_bounds__(256, 2) k_node_update(
    const float* __restrict__ agg,
    const float* __restrict__ lin2w, const float* __restrict__ lin2b,
    const float* __restrict__ linw, const float* __restrict__ linb,
    int N, float* __restrict__ h) {
    int n = blockIdx.x * blockDim.x + threadIdx.x;
    if (n >= N) return;
    float av[64];
    const float4* ar = (const float4*)(agg + (size_t)n * FIL);
#pragma unroll
    for (int c = 0; c < 16; c++) {
        float4 v = ar[c];
        av[c * 4 + 0] = v.x; av[c * 4 + 1] = v.y; av[c * 4 + 2] = v.z; av[c * 4 + 3] = v.w;
    }
    float tv[64];
#pragma unroll 2
    for (int f = 0; f < HID; f++) {
        float acc = lin2b[f];
#pragma unroll
        for (int j = 0; j < FIL; j++) acc += av[j] * lin2w[f * FIL + j];
        tv[f] = sspf(acc);
    }
    float4* hr = (float4*)(h + (size_t)n * HID);
#pragma unroll 2
    for (int c = 0; c < 16; c++) {
        float4 hvv = hr[c];
        float* hp = (float*)&hvv;
#pragma unroll
        for (int q = 0; q < 4; q++) {
            int f = c * 4 + q;
            float acc = linb[f];
#pragma unroll
            for (int j = 0; j < HID; j++) acc += tv[j] * linw[f * HID + j];
            hp[q] += acc;
        }
        hr[c] = hvv;
    }
}

// ---------------- readout MLP + scatter mean accumulation ----------------
__global__ void __launch_bounds__(256, 2) k_readout(
    const float* __restrict__ h, const int* __restrict__ batch,
    const float* __restrict__ w1, const float* __restrict__ b1,
    const float* __restrict__ w2, const float* __restrict__ b2,
    int N, float* __restrict__ sums, float* __restrict__ counts) {
    int n = blockIdx.x * blockDim.x + threadIdx.x;
    if (n >= N) return;
    float hv[64];
    const float4* hr = (const float4*)(h + (size_t)n * HID);
#pragma unroll
    for (int c = 0; c < 16; c++) {
        float4 v = hr[c];
        hv[c * 4 + 0] = v.x; hv[c * 4 + 1] = v.y; hv[c * 4 + 2] = v.z; hv[c * 4 + 3] = v.w;
    }
    float o = b2[0];
#pragma unroll 2
    for (int j = 0; j < 32; j++) {
        float acc = b1[j];
#pragma unroll
        for (int k = 0; k < 64; k++) acc += hv[k] * w1[j * 64 + k];
        o += sspf(acc) * w2[j];
    }
    int b = batch[n];
    unsafeAtomicAdd(&sums[b], o);
    unsafeAtomicAdd(&counts[b], 1.0f);
}

__global__ void k_finalize(const float* __restrict__ sums, const float* __restrict__ counts,
                           int G, float* __restrict__ out) {
    int g = blockIdx.x * blockDim.x + threadIdx.x;
    if (g >= G) return;
    out[g] = sums[g] / fmaxf(counts[g], 1.0f);
}

extern "C" void kernel_launch(void* const* d_in, const int* in_sizes, int n_in,
                              void* d_out, int out_size, void* d_ws, size_t ws_size,
                              hipStream_t stream) {
    const float* pos    = (const float*)d_in[0];
    const float* shifts = (const float*)d_in[1];
    const float* attrs  = (const float*)d_in[2];
    const int*   batch  = (const int*)d_in[3];
    const int*   ei     = (const int*)d_in[4];
    const float* wv     = (const float*)d_in[5];
    const float* mlp_w1 = (const float*)d_in[6];
    const float* mlp_b1 = (const float*)d_in[7];
    const float* mlp_w2 = (const float*)d_in[8];
    const float* mlp_b2 = (const float*)d_in[9];
    const float* lin1w  = (const float*)d_in[10];
    const float* lin2w  = (const float*)d_in[11];
    const float* lin2b  = (const float*)d_in[12];
    const float* linw   = (const float*)d_in[13];
    const float* linb   = (const float*)d_in[14];
    const float* ow1    = (const float*)d_in[15];
    const float* ob1    = (const float*)d_in[16];
    const float* ow2    = (const float*)d_in[17];
    const float* ob2    = (const float*)d_in[18];

    const int N = in_sizes[0] / 3;       // 100000
    const int E = in_sizes[4] / 2;       // 1600000
    const int G = out_size;              // 1000

    char* w = (char*)d_ws;
    size_t off = 0;
    auto alloc = [&](size_t bytes) -> char* {
        char* p = w + off;
        off = (off + bytes + 255) & ~(size_t)255;
        return p;
    };
    int*   cnt       = (int*)alloc((size_t)N * 4);
    int*   row_start = (int*)alloc((size_t)(N + 1) * 4);
    int*   cursor    = (int*)alloc((size_t)N * 4);
    int*   src_s     = (int*)alloc((size_t)E * 4);
    float* d_s       = (float*)alloc((size_t)E * 4);
    float* c_s       = (float*)alloc((size_t)E * 4);
    float* h         = (float*)alloc((size_t)N * HID * 4);
    float* xf        = (float*)alloc((size_t)N * FIL * 4);
    float* agg       = (float*)alloc((size_t)N * FIL * 4);
    float* w2T       = (float*)alloc((size_t)2 * 64 * 64 * 4);
    float* sums      = (float*)alloc((size_t)G * 4);
    float* cnts      = (float*)alloc((size_t)G * 4);
    size_t fixed = off;
    size_t avail = ws_size > fixed ? ws_size - fixed : 0;
    long long chunkE = (long long)(avail / (FIL * 4)) & ~63LL;
    if (chunkE > E) chunkE = E;
    // cap msgbuf at ~64MB (256K edges) so edge_mlp->segsum round-trip stays L3-resident
    if (chunkE > 262144) chunkE = 262144;
    bool chunked = chunkE >= 4096;
    float* msgbuf = (float*)(w + fixed);

    const int B = 256;
    k_transpose_w2<<<(2 * 64 * 64 + B - 1) / B, B, 0, stream>>>(mlp_w2, w2T);
    k_embed<<<(N + B - 1) / B, B, 0, stream>>>(attrs, wv, N, h);

    if (chunked) {
        hipMemsetAsync(cnt, 0, (size_t)N * 4, stream);
        k_count<<<(E + B - 1) / B, B, 0, stream>>>(ei, E, cnt);
        k_scan<<<1, 1024, 0, stream>>>(cnt, N, row_start, cursor);
        k_fill<<<(E + B - 1) / B, B, 0, stream>>>(pos, shifts, ei, E, cursor, src_s, d_s, c_s);

        for (int l = 0; l < 2; l++) {
            k_lin1<<<(N + B - 1) / B, B, 0, stream>>>(h, lin1w + l * 4096, N, xf);
            hipMemsetAsync(agg, 0, (size_t)N * FIL * 4, stream);
            for (long long c0 = 0; c0 < E; c0 += chunkE) {
                int cc = (int)((E - c0 < chunkE) ? (E - c0) : chunkE);
                k_edge_mlp<<<(cc + B - 1) / B, B, 0, stream>>>(
                    d_s, c_s, src_s, (int)c0, cc,
                    mlp_w1 + l * 64 * NBASES, mlp_b1 + l * 64,
                    w2T + l * 4096, mlp_b2 + l * 64, xf, msgbuf);
                k_segsum<<<((size_t)N * 64 + B - 1) / B, B, 0, stream>>>(
                    row_start, N, (int)c0, (int)(c0 + cc), msgbuf, agg);
            }
            k_node_update<<<(N + B - 1) / B, B, 0, stream>>>(
                agg, lin2w + l * 4096, lin2b + l * 64, linw + l * 4096, linb + l * 64, N, h);
        }
    } else {
        // fallback: original atomic-scatter path (reuses d_s/c_s as unsorted geo arrays)
        k_edge_geo<<<(E + B - 1) / B, B, 0, stream>>>(pos, shifts, ei, E, d_s, c_s);
        for (int l = 0; l < 2; l++) {
            k_lin1<<<(N + B - 1) / B, B, 0, stream>>>(h, lin1w + l * 4096, N, xf);
            hipMemsetAsync(agg, 0, (size_t)N * FIL * 4, stream);
            k_edge_msg_atomic<<<(E + B - 1) / B, B, 0, stream>>>(
                d_s, c_s, ei, E,
                mlp_w1 + l * 64 * NBASES, mlp_b1 + l * 64,
                w2T + l * 4096, mlp_b2 + l * 64, xf, agg);
            k_node_update<<<(N + B - 1) / B, B, 0, stream>>>(
                agg, lin2w + l * 4096, lin2b + l * 64, linw + l * 4096, linb + l * 64, N, h);
        }
    }

    hipMemsetAsync(sums, 0, (size_t)G * 4, stream);
    hipMemsetAsync(cnts, 0, (size_t)G * 4, stream);
    k_readout<<<(N + B - 1) / B, B, 0, stream>>>(h, batch, ow1, ob1, ow2, ob2, N, sums, cnts);
    k_finalize<<<(G + B - 1) / B, B, 0, stream>>>(sums, cnts, G, (float*)d_out);
}

// Round 4
// 1313.702 us; speedup vs baseline: 9.2142x; 1.8463x over previous
//
#include <hip/hip_runtime.h>
#include <math.h>

#define NBASES 16
#define HID 64
#define FIL 64
#define TBL 8192
#define DMAX 8.0f
// table scale: entries at d_i = i * DMAX/(TBL-1)
#define TSCALE (8191.0f / 8.0f)

// ShiftedSoftplus: softplus(x) - log(2), overflow-safe form.
__device__ __forceinline__ float sspf(float x) {
    return fmaxf(x, 0.f) + __logf(1.f + __expf(-fabsf(x))) - 0.69314718056f;
}

// ---------------- CSR build: histogram of dst ----------------
__global__ void k_count(const int* __restrict__ ei, int E, int* __restrict__ cnt) {
    int e = blockIdx.x * blockDim.x + threadIdx.x;
    if (e >= E) return;
    atomicAdd(&cnt[ei[E + e]], 1);
}

// ---- 3-phase scan: per-block exclusive scan + carry, carry scan, add ----
__global__ void k_scan_blk(const int* __restrict__ cnt, int N,
                           int* __restrict__ row_start, int* __restrict__ carry) {
    __shared__ int s[1024];
    int tid = threadIdx.x;
    int idx = blockIdx.x * 1024 + tid;
    int v = (idx < N) ? cnt[idx] : 0;
    s[tid] = v;
    __syncthreads();
    for (int off = 1; off < 1024; off <<= 1) {
        int t = (tid >= off) ? s[tid - off] : 0;
        __syncthreads();
        s[tid] += t;
        __syncthreads();
    }
    if (idx < N) row_start[idx] = s[tid] - v;     // within-block exclusive
    if (tid == 1023) carry[blockIdx.x] = s[1023]; // block total
}

__global__ void k_scan_carry(const int* __restrict__ carry, int nblk,
                             int* __restrict__ carry_ex) {
    __shared__ int s[1024];
    int tid = threadIdx.x;
    int v = (tid < nblk) ? carry[tid] : 0;
    s[tid] = v;
    __syncthreads();
    for (int off = 1; off < 1024; off <<= 1) {
        int t = (tid >= off) ? s[tid - off] : 0;
        __syncthreads();
        s[tid] += t;
        __syncthreads();
    }
    if (tid < nblk) carry_ex[tid] = s[tid] - v;
}

__global__ void k_scan_add(int* __restrict__ row_start, const int* __restrict__ carry_ex,
                           int N, int E, int* __restrict__ cursor) {
    int i = blockIdx.x * blockDim.x + threadIdx.x;
    if (i >= N) return;
    int r = row_start[i] + carry_ex[i >> 10];
    row_start[i] = r;
    cursor[i] = r;
    if (i == 0) row_start[N] = E;
}

// fill sorted-edge records: {src, dst, d, C} packed in one float4
__global__ void k_fill(const float* __restrict__ pos, const float* __restrict__ shifts,
                       const int* __restrict__ ei, int E, int* __restrict__ cursor,
                       float4* __restrict__ e_pack) {
    int e = blockIdx.x * blockDim.x + threadIdx.x;
    if (e >= E) return;
    int s = ei[e], t = ei[E + e];
    float dx = pos[t * 3 + 0] - pos[s * 3 + 0] + shifts[e * 3 + 0];
    float dy = pos[t * 3 + 1] - pos[s * 3 + 1] + shifts[e * 3 + 1];
    float dz = pos[t * 3 + 2] - pos[s * 3 + 2] + shifts[e * 3 + 2];
    float d = sqrtf(dx * dx + dy * dy + dz * dz);
    float C = 0.5f * (cosf(d * 0.6283185307179586f) + 1.0f); // pi/CUTOFF = pi/5
    int p = atomicAdd(&cursor[t], 1);
    float4 rec;
    rec.x = __int_as_float(s);
    rec.y = __int_as_float(t);
    rec.z = d;
    rec.w = C;
    e_pack[p] = rec;
}

// ---------------- build W(d) lookup table per layer (the filter MLP on a d-grid) ----------------
__global__ void __launch_bounds__(256, 2) k_table(
    const float* __restrict__ w1, const float* __restrict__ b1,
    const float* __restrict__ w2, const float* __restrict__ b2,
    float* __restrict__ tab) {
    int i = blockIdx.x * blockDim.x + threadIdx.x; // l*TBL + ti
    if (i >= 2 * TBL) return;
    int l = i >> 13, ti = i & (TBL - 1);
    const float* w1l = w1 + l * (FIL * NBASES);
    const float* b1l = b1 + l * FIL;
    const float* w2l = w2 + l * (FIL * FIL);
    const float* b2l = b2 + l * FIL;
    float d = (float)ti * (DMAX / (float)(TBL - 1));
    float g[16];
#pragma unroll
    for (int b = 0; b < NBASES; b++) {
        float u = d - (float)b * (5.0f / 15.0f);
        g[b] = __expf(-4.5f * u * u);
    }
    float hid[64];
#pragma unroll 4
    for (int j = 0; j < FIL; j++) {
        float tt = b1l[j];
#pragma unroll
        for (int b = 0; b < NBASES; b++) tt += w1l[j * NBASES + b] * g[b];
        hid[j] = sspf(tt);
    }
    float4* out = (float4*)(tab + (size_t)i * FIL);
#pragma unroll 2
    for (int c = 0; c < 16; c++) {
        float4 o;
        float* op = (float*)&o;
#pragma unroll
        for (int q = 0; q < 4; q++) {
            int f = c * 4 + q;
            float acc = b2l[f];
#pragma unroll
            for (int j = 0; j < FIL; j++) acc += w2l[f * FIL + j] * hid[j];
            op[q] = acc;
        }
        out[c] = o;
    }
}

// ---------------- node embedding: h = node_attrs @ W_v^T ----------------
__global__ void k_embed(const float* __restrict__ attrs, const float* __restrict__ wv,
                        int N, float* __restrict__ h) {
    int n = blockIdx.x * blockDim.x + threadIdx.x;
    if (n >= N) return;
    float a[5];
#pragma unroll
    for (int s = 0; s < 5; s++) a[s] = attrs[n * 5 + s];
    float4* out = (float4*)(h + (size_t)n * HID);
#pragma unroll 4
    for (int c = 0; c < 16; c++) {
        float4 o;
        float* op = (float*)&o;
#pragma unroll
        for (int q = 0; q < 4; q++) {
            int f = c * 4 + q;
            float acc = 0.f;
#pragma unroll
            for (int s = 0; s < 5; s++) acc += a[s] * wv[f * 5 + s];
            op[q] = acc;
        }
        out[c] = o;
    }
}

// ---------------- xf = h @ lin1_w^T (no bias); chunked accs keep liveness ~80 regs ----------------
__global__ void __launch_bounds__(256, 2) k_lin1(
    const float* __restrict__ h, const float* __restrict__ w,
    int N, float* __restrict__ xf) {
    int n = blockIdx.x * blockDim.x + threadIdx.x;
    if (n >= N) return;
    float hv[64];
    const float4* hr = (const float4*)(h + (size_t)n * HID);
#pragma unroll
    for (int c = 0; c < 16; c++) {
        float4 v = hr[c];
        hv[c * 4 + 0] = v.x; hv[c * 4 + 1] = v.y; hv[c * 4 + 2] = v.z; hv[c * 4 + 3] = v.w;
    }
    float4* out = (float4*)(xf + (size_t)n * FIL);
#pragma unroll 2
    for (int c = 0; c < 16; c++) {
        float4 o;
        float* op = (float*)&o;
#pragma unroll
        for (int q = 0; q < 4; q++) {
            int f = c * 4 + q;
            float acc = 0.f;
#pragma unroll
            for (int j = 0; j < 64; j++) acc += hv[j] * w[f * 64 + j];
            op[q] = acc;
        }
        out[c] = o;
    }
}

// ---------------- fused: table-lookup filter * xf[src] -> LDS -> in-block segment sum ----------------
// 256 edges/block. LDS tile XOR-swizzled: word (t*64 + 4*(c ^ (t&15)) + q) -> 2-way max.
__global__ void __launch_bounds__(256, 2) k_edge_fused(
    const float4* __restrict__ e_pack, const int* __restrict__ row_start, int E,
    const float* __restrict__ tab, const float* __restrict__ xf, float* __restrict__ agg) {
    __shared__ float lds[256 * 64]; // 64 KB
    int t = threadIdx.x;
    int e0 = blockIdx.x * 256;
    int e1 = e0 + 256; if (e1 > E) e1 = E;
    int e = e0 + t;

    if (e < E) {
        float4 ep = e_pack[e];
        int s = __float_as_int(ep.x);
        float dv = ep.z, cv = ep.w;
        float x = dv * TSCALE;
        int i0 = (int)x; if (i0 > TBL - 2) i0 = TBL - 2;
        float fr = x - (float)i0; fr = fminf(fr, 1.0f);
        const float4* r0 = (const float4*)(tab + (size_t)i0 * FIL);
        const float4* r1 = r0 + 16;
        const float4* xr = (const float4*)(xf + (size_t)s * FIL);
        float* Lrow = lds + t * 64;
        int k = t & 15;
#pragma unroll
        for (int c = 0; c < 16; c++) {
            float4 a0 = r0[c], a1 = r1[c], xv = xr[c];
            float4 m;
            m.x = xv.x * (a0.x + (a1.x - a0.x) * fr) * cv;
            m.y = xv.y * (a0.y + (a1.y - a0.y) * fr) * cv;
            m.z = xv.z * (a0.z + (a1.z - a0.z) * fr) * cv;
            m.w = xv.w * (a0.w + (a1.w - a0.w) * fr) * cv;
            *(float4*)(Lrow + ((c ^ k) << 2)) = m;
        }
    }
    __syncthreads();

    // segment-sum phase: 4 waves, lane = filter index
    int wid = t >> 6, lane = t & 63;
    int n_lo = __float_as_int(e_pack[e0].y);
    int n_hi = __float_as_int(e_pack[e1 - 1].y);
    int fq = lane >> 2, fr4 = lane & 3;
    for (int n = n_lo + wid; n <= n_hi; n += 4) {
        int rs = row_start[n], re = row_start[n + 1];
        int lo = rs > e0 ? rs : e0;
        int hi = re < e1 ? re : e1;
        if (lo >= hi) continue;
        float a = 0.f;
        for (int r = lo; r < hi; r++) {
            int slot = r - e0;
            a += lds[slot * 64 + (((fq ^ (slot & 15)) << 2) | fr4)];
        }
        float* dp = agg + (size_t)n * FIL + lane;
        if (rs >= e0 && re <= e1) *dp = a;
        else unsafeAtomicAdd(dp, a);
    }
}

// ---------------- node update split A: tmp = ssp(lin2(agg)) ----------------
__global__ void __launch_bounds__(256, 2) k_nu_a(
    const float* __restrict__ agg, const float* __restrict__ w, const float* __restrict__ b,
    int N, float* __restrict__ tmp) {
    int n = blockIdx.x * blockDim.x + threadIdx.x;
    if (n >= N) return;
    float av[64];
    const float4* ar = (const float4*)(agg + (size_t)n * FIL);
#pragma unroll
    for (int c = 0; c < 16; c++) {
        float4 v = ar[c];
        av[c * 4 + 0] = v.x; av[c * 4 + 1] = v.y; av[c * 4 + 2] = v.z; av[c * 4 + 3] = v.w;
    }
    float4* out = (float4*)(tmp + (size_t)n * HID);
#pragma unroll 2
    for (int c = 0; c < 16; c++) {
        float4 o;
        float* op = (float*)&o;
#pragma unroll
        for (int q = 0; q < 4; q++) {
            int f = c * 4 + q;
            float acc = b[f];
#pragma unroll
            for (int j = 0; j < 64; j++) acc += av[j] * w[f * 64 + j];
            op[q] = sspf(acc);
        }
        out[c] = o;
    }
}

// ---------------- node update split B: h += lin(tmp) ----------------
__global__ void __launch_bounds__(256, 2) k_nu_b(
    const float* __restrict__ tmp, const float* __restrict__ w, const float* __restrict__ b,
    int N, float* __restrict__ h) {
    int n = blockIdx.x * blockDim.x + threadIdx.x;
    if (n >= N) return;
    float tv[64];
    const float4* tr = (const float4*)(tmp + (size_t)n * HID);
#pragma unroll
    for (int c = 0; c < 16; c++) {
        float4 v = tr[c];
        tv[c * 4 + 0] = v.x; tv[c * 4 + 1] = v.y; tv[c * 4 + 2] = v.z; tv[c * 4 + 3] = v.w;
    }
    float4* hr = (float4*)(h + (size_t)n * HID);
#pragma unroll 2
    for (int c = 0; c < 16; c++) {
        float4 hv = hr[c];
        float* hp = (float*)&hv;
#pragma unroll
        for (int q = 0; q < 4; q++) {
            int f = c * 4 + q;
            float acc = b[f];
#pragma unroll
            for (int j = 0; j < 64; j++) acc += tv[j] * w[f * 64 + j];
            hp[q] += acc;
        }
        hr[c] = hv;
    }
}

// ---------------- readout MLP + scatter mean accumulation ----------------
__global__ void __launch_bounds__(256, 2) k_readout(
    const float* __restrict__ h, const int* __restrict__ batch,
    const float* __restrict__ w1, const float* __restrict__ b1,
    const float* __restrict__ w2, const float* __restrict__ b2,
    int N, float* __restrict__ sums, float* __restrict__ counts) {
    int n = blockIdx.x * blockDim.x + threadIdx.x;
    if (n >= N) return;
    float hv[64];
    const float4* hr = (const float4*)(h + (size_t)n * HID);
#pragma unroll
    for (int c = 0; c < 16; c++) {
        float4 v = hr[c];
        hv[c * 4 + 0] = v.x; hv[c * 4 + 1] = v.y; hv[c * 4 + 2] = v.z; hv[c * 4 + 3] = v.w;
    }
    float o = b2[0];
#pragma unroll 2
    for (int j = 0; j < 32; j++) {
        float acc = b1[j];
#pragma unroll
        for (int k = 0; k < 64; k++) acc += hv[k] * w1[j * 64 + k];
        o += sspf(acc) * w2[j];
    }
    int b = batch[n];
    unsafeAtomicAdd(&sums[b], o);
    unsafeAtomicAdd(&counts[b], 1.0f);
}

__global__ void k_finalize(const float* __restrict__ sums, const float* __restrict__ counts,
                           int G, float* __restrict__ out) {
    int g = blockIdx.x * blockDim.x + threadIdx.x;
    if (g >= G) return;
    out[g] = sums[g] / fmaxf(counts[g], 1.0f);
}

extern "C" void kernel_launch(void* const* d_in, const int* in_sizes, int n_in,
                              void* d_out, int out_size, void* d_ws, size_t ws_size,
                              hipStream_t stream) {
    const float* pos    = (const float*)d_in[0];
    const float* shifts = (const float*)d_in[1];
    const float* attrs  = (const float*)d_in[2];
    const int*   batch  = (const int*)d_in[3];
    const int*   ei     = (const int*)d_in[4];
    const float* wv     = (const float*)d_in[5];
    const float* mlp_w1 = (const float*)d_in[6];
    const float* mlp_b1 = (const float*)d_in[7];
    const float* mlp_w2 = (const float*)d_in[8];
    const float* mlp_b2 = (const float*)d_in[9];
    const float* lin1w  = (const float*)d_in[10];
    const float* lin2w  = (const float*)d_in[11];
    const float* lin2b  = (const float*)d_in[12];
    const float* linw   = (const float*)d_in[13];
    const float* linb   = (const float*)d_in[14];
    const float* ow1    = (const float*)d_in[15];
    const float* ob1    = (const float*)d_in[16];
    const float* ow2    = (const float*)d_in[17];
    const float* ob2    = (const float*)d_in[18];

    const int N = in_sizes[0] / 3;       // 100000
    const int E = in_sizes[4] / 2;       // 1600000
    const int G = out_size;              // 1000

    char* w = (char*)d_ws;
    size_t off = 0;
    auto alloc = [&](size_t bytes) -> char* {
        char* p = w + off;
        off = (off + bytes + 255) & ~(size_t)255;
        return p;
    };
    int*    cnt       = (int*)alloc((size_t)N * 4);
    int*    row_start = (int*)alloc((size_t)(N + 1) * 4);
    int*    cursor    = (int*)alloc((size_t)N * 4);
    int*    carry     = (int*)alloc(1024 * 4);
    int*    carry_ex  = (int*)alloc(1024 * 4);
    float4* e_pack    = (float4*)alloc((size_t)E * 16);
    float*  h         = (float*)alloc((size_t)N * HID * 4);
    float*  xf        = (float*)alloc((size_t)N * FIL * 4);   // also reused as tmp in nu_a/nu_b
    float*  agg       = (float*)alloc((size_t)N * FIL * 4);
    float*  tab       = (float*)alloc((size_t)2 * TBL * FIL * 4); // 4.2 MB
    float*  sums      = (float*)alloc((size_t)G * 4);
    float*  cnts      = (float*)alloc((size_t)G * 4);
    (void)ws_size;

    const int B = 256;
    const int nblk = (N + 1023) / 1024;

    // CSR build (once per call; ws re-poisoned each call)
    hipMemsetAsync(cnt, 0, (size_t)N * 4, stream);
    k_count<<<(E + B - 1) / B, B, 0, stream>>>(ei, E, cnt);
    k_scan_blk<<<nblk, 1024, 0, stream>>>(cnt, N, row_start, carry);
    k_scan_carry<<<1, 1024, 0, stream>>>(carry, nblk, carry_ex);
    k_scan_add<<<(N + B - 1) / B, B, 0, stream>>>(row_start, carry_ex, N, E, cursor);
    k_fill<<<(E + B - 1) / B, B, 0, stream>>>(pos, shifts, ei, E, cursor, e_pack);

    // W(d) tables for both layers + embedding
    k_table<<<(2 * TBL + B - 1) / B, B, 0, stream>>>(mlp_w1, mlp_b1, mlp_w2, mlp_b2, tab);
    k_embed<<<(N + B - 1) / B, B, 0, stream>>>(attrs, wv, N, h);

    for (int l = 0; l < 2; l++) {
        k_lin1<<<(N + B - 1) / B, B, 0, stream>>>(h, lin1w + l * 4096, N, xf);
        hipMemsetAsync(agg, 0, (size_t)N * FIL * 4, stream);
        k_edge_fused<<<(E + 255) / 256, 256, 0, stream>>>(
            e_pack, row_start, E, tab + (size_t)l * TBL * FIL, xf, agg);
        k_nu_a<<<(N + B - 1) / B, B, 0, stream>>>(agg, lin2w + l * 4096, lin2b + l * 64, N, xf);
        k_nu_b<<<(N + B - 1) / B, B, 0, stream>>>(xf, linw + l * 4096, linb + l * 64, N, h);
    }

    hipMemsetAsync(sums, 0, (size_t)G * 4, stream);
    hipMemsetAsync(cnts, 0, (size_t)G * 4, stream);
    k_readout<<<(N + B - 1) / B, B, 0, stream>>>(h, batch, ow1, ob1, ow2, ob2, N, sums, cnts);
    k_finalize<<<(G + B - 1) / B, B, 0, stream>>>(sums, cnts, G, (float*)d_out);
}

// Round 5
// 1184.413 us; speedup vs baseline: 10.2200x; 1.1092x over previous
//
#include <hip/hip_runtime.h>
#include <math.h>

#define NBASES 16
#define HID 64
#define FIL 64
#define TBL 8192
#define DMAX 8.0f
#define TSCALE (8191.0f / 8.0f)

// ShiftedSoftplus: softplus(x) - log(2), overflow-safe form.
__device__ __forceinline__ float sspf(float x) {
    return fmaxf(x, 0.f) + __logf(1.f + __expf(-fabsf(x))) - 0.69314718056f;
}

// ---------------- CSR build: histogram of dst ----------------
__global__ void k_count(const int* __restrict__ ei, int E, int* __restrict__ cnt) {
    int e = blockIdx.x * blockDim.x + threadIdx.x;
    if (e >= E) return;
    atomicAdd(&cnt[ei[E + e]], 1);
}

// ---- 3-phase scan: per-block exclusive scan + carry, carry scan, add ----
__global__ void k_scan_blk(const int* __restrict__ cnt, int N,
                           int* __restrict__ row_start, int* __restrict__ carry) {
    __shared__ int s[1024];
    int tid = threadIdx.x;
    int idx = blockIdx.x * 1024 + tid;
    int v = (idx < N) ? cnt[idx] : 0;
    s[tid] = v;
    __syncthreads();
    for (int off = 1; off < 1024; off <<= 1) {
        int t = (tid >= off) ? s[tid - off] : 0;
        __syncthreads();
        s[tid] += t;
        __syncthreads();
    }
    if (idx < N) row_start[idx] = s[tid] - v;     // within-block exclusive
    if (tid == 1023) carry[blockIdx.x] = s[1023]; // block total
}

__global__ void k_scan_carry(const int* __restrict__ carry, int nblk,
                             int* __restrict__ carry_ex) {
    __shared__ int s[1024];
    int tid = threadIdx.x;
    int v = (tid < nblk) ? carry[tid] : 0;
    s[tid] = v;
    __syncthreads();
    for (int off = 1; off < 1024; off <<= 1) {
        int t = (tid >= off) ? s[tid - off] : 0;
        __syncthreads();
        s[tid] += t;
        __syncthreads();
    }
    if (tid < nblk) carry_ex[tid] = s[tid] - v;
}

__global__ void k_scan_add(int* __restrict__ row_start, const int* __restrict__ carry_ex,
                           int N, int E, int* __restrict__ cursor) {
    int i = blockIdx.x * blockDim.x + threadIdx.x;
    if (i >= N) return;
    int r = row_start[i] + carry_ex[i >> 10];
    row_start[i] = r;
    cursor[i] = r;
    if (i == 0) row_start[N] = E;
}

// fill sorted-edge records: {src, dst, d, C} packed in one float4
__global__ void k_fill(const float* __restrict__ pos, const float* __restrict__ shifts,
                       const int* __restrict__ ei, int E, int* __restrict__ cursor,
                       float4* __restrict__ e_pack) {
    int e = blockIdx.x * blockDim.x + threadIdx.x;
    if (e >= E) return;
    int s = ei[e], t = ei[E + e];
    float dx = pos[t * 3 + 0] - pos[s * 3 + 0] + shifts[e * 3 + 0];
    float dy = pos[t * 3 + 1] - pos[s * 3 + 1] + shifts[e * 3 + 1];
    float dz = pos[t * 3 + 2] - pos[s * 3 + 2] + shifts[e * 3 + 2];
    float d = sqrtf(dx * dx + dy * dy + dz * dz);
    float C = 0.5f * (cosf(d * 0.6283185307179586f) + 1.0f); // pi/CUTOFF = pi/5
    int p = atomicAdd(&cursor[t], 1);
    float4 rec;
    rec.x = __int_as_float(s);
    rec.y = __int_as_float(t);
    rec.z = d;
    rec.w = C;
    e_pack[p] = rec;
}

// ---------------- W(d) lookup tables: thread = (entry, 4-filter chunk); no hid[] array ----------------
__global__ void __launch_bounds__(256) k_table(
    const float* __restrict__ w1, const float* __restrict__ b1,
    const float* __restrict__ w2, const float* __restrict__ b2,
    float* __restrict__ tab) {
    int i = blockIdx.x * blockDim.x + threadIdx.x; // ((l*TBL + ti)<<4) | chunk
    if (i >= 2 * TBL * 16) return;
    int chunk = i & 15;
    int ent = i >> 4;
    int l = ent >> 13;
    int ti = ent & (TBL - 1);
    int f0 = chunk * 4;
    const float* w1l = w1 + l * (FIL * NBASES);
    const float* b1l = b1 + l * FIL;
    const float* w2l = w2 + l * (FIL * FIL);
    const float* b2l = b2 + l * FIL;
    float d = (float)ti * (DMAX / (float)(TBL - 1));
    float g[16];
#pragma unroll
    for (int b = 0; b < NBASES; b++) {
        float u = d - (float)b * (5.0f / 15.0f);
        g[b] = __expf(-4.5f * u * u);
    }
    float a0 = b2l[f0 + 0], a1 = b2l[f0 + 1], a2 = b2l[f0 + 2], a3 = b2l[f0 + 3];
#pragma unroll 4
    for (int j = 0; j < FIL; j++) {
        float tt = b1l[j];
#pragma unroll
        for (int b = 0; b < NBASES; b++) tt += w1l[j * NBASES + b] * g[b];
        float hj = sspf(tt);
        a0 += w2l[(f0 + 0) * FIL + j] * hj;
        a1 += w2l[(f0 + 1) * FIL + j] * hj;
        a2 += w2l[(f0 + 2) * FIL + j] * hj;
        a3 += w2l[(f0 + 3) * FIL + j] * hj;
    }
    float4 o; o.x = a0; o.y = a1; o.z = a2; o.w = a3;
    *(float4*)(tab + (size_t)ent * FIL + f0) = o;
}

// ---------------- fused embed + layer0 lin1: h = attrs@Wv^T; xf = h@lin1_0^T ----------------
__global__ void __launch_bounds__(256, 2) k_embed_lin1(
    const float* __restrict__ attrs, const float* __restrict__ wv,
    const float* __restrict__ w, int N,
    float* __restrict__ h, float* __restrict__ xf) {
    int n = blockIdx.x * blockDim.x + threadIdx.x;
    if (n >= N) return;
    float a[5];
#pragma unroll
    for (int s = 0; s < 5; s++) a[s] = attrs[n * 5 + s];
    float hv[64];
#pragma unroll 4
    for (int f = 0; f < HID; f++) {
        float acc = 0.f;
#pragma unroll
        for (int s = 0; s < 5; s++) acc += a[s] * wv[f * 5 + s];
        hv[f] = acc;
    }
    float4* hout = (float4*)(h + (size_t)n * HID);
#pragma unroll
    for (int c = 0; c < 16; c++) {
        float4 o; o.x = hv[c*4+0]; o.y = hv[c*4+1]; o.z = hv[c*4+2]; o.w = hv[c*4+3];
        hout[c] = o;
    }
    float4* out = (float4*)(xf + (size_t)n * FIL);
#pragma unroll 2
    for (int c = 0; c < 16; c++) {
        float4 o;
        float* op = (float*)&o;
#pragma unroll
        for (int q = 0; q < 4; q++) {
            int f = c * 4 + q;
            float acc = 0.f;
#pragma unroll
            for (int j = 0; j < 64; j++) acc += hv[j] * w[f * 64 + j];
            op[q] = acc;
        }
        out[c] = o;
    }
}

// ---------------- xf = h @ lin1_w^T (no bias) ----------------
__global__ void __launch_bounds__(256, 2) k_lin1(
    const float* __restrict__ h, const float* __restrict__ w,
    int N, float* __restrict__ xf) {
    int n = blockIdx.x * blockDim.x + threadIdx.x;
    if (n >= N) return;
    float hv[64];
    const float4* hr = (const float4*)(h + (size_t)n * HID);
#pragma unroll
    for (int c = 0; c < 16; c++) {
        float4 v = hr[c];
        hv[c * 4 + 0] = v.x; hv[c * 4 + 1] = v.y; hv[c * 4 + 2] = v.z; hv[c * 4 + 3] = v.w;
    }
    float4* out = (float4*)(xf + (size_t)n * FIL);
#pragma unroll 2
    for (int c = 0; c < 16; c++) {
        float4 o;
        float* op = (float*)&o;
#pragma unroll
        for (int q = 0; q < 4; q++) {
            int f = c * 4 + q;
            float acc = 0.f;
#pragma unroll
            for (int j = 0; j < 64; j++) acc += hv[j] * w[f * 64 + j];
            op[q] = acc;
        }
        out[c] = o;
    }
}

// ---------------- edge aggregate: wave per node, lane = filter; coalesced gathers, no LDS/atomics ----------------
// agg[n][lane] = sum over dst-sorted run [row_start[n], row_start[n+1]) of xf[src][lane]*lerp(tab,d)[lane]*C
__global__ void __launch_bounds__(256, 8) k_edge_agg(
    const float4* __restrict__ e_pack, const int* __restrict__ row_start, int N,
    const float* __restrict__ tab, const float* __restrict__ xf, float* __restrict__ agg) {
    int n = (blockIdx.x * blockDim.x + threadIdx.x) >> 6;
    int lane = threadIdx.x & 63;
    if (n >= N) return;
    int rs = row_start[n], re = row_start[n + 1];
    float acc = 0.f;
    for (int r = rs; r < re; r++) {
        float4 ep = e_pack[r];                 // wave-uniform address -> broadcast fetch
        int s = __float_as_int(ep.x);
        float x = ep.z * TSCALE;
        int i0 = (int)x; if (i0 > TBL - 2) i0 = TBL - 2;
        float fr = fminf(x - (float)i0, 1.0f);
        float t0 = tab[(size_t)i0 * FIL + lane];        // coalesced 256B row
        float t1 = tab[(size_t)(i0 + 1) * FIL + lane];  // coalesced 256B row
        float xv = xf[(size_t)s * FIL + lane];          // coalesced 256B row
        acc += xv * (t0 + (t1 - t0) * fr) * ep.w;
    }
    agg[(size_t)n * FIL + lane] = acc;          // plain store; covers all nodes (no memset needed)
}

// ---------------- node update split A: tmp = ssp(lin2(agg)) ----------------
__global__ void __launch_bounds__(256, 2) k_nu_a(
    const float* __restrict__ agg, const float* __restrict__ w, const float* __restrict__ b,
    int N, float* __restrict__ tmp) {
    int n = blockIdx.x * blockDim.x + threadIdx.x;
    if (n >= N) return;
    float av[64];
    const float4* ar = (const float4*)(agg + (size_t)n * FIL);
#pragma unroll
    for (int c = 0; c < 16; c++) {
        float4 v = ar[c];
        av[c * 4 + 0] = v.x; av[c * 4 + 1] = v.y; av[c * 4 + 2] = v.z; av[c * 4 + 3] = v.w;
    }
    float4* out = (float4*)(tmp + (size_t)n * HID);
#pragma unroll 2
    for (int c = 0; c < 16; c++) {
        float4 o;
        float* op = (float*)&o;
#pragma unroll
        for (int q = 0; q < 4; q++) {
            int f = c * 4 + q;
            float acc = b[f];
#pragma unroll
            for (int j = 0; j < 64; j++) acc += av[j] * w[f * 64 + j];
            op[q] = sspf(acc);
        }
        out[c] = o;
    }
}

// ---------------- node update split B: h += lin(tmp) ----------------
__global__ void __launch_bounds__(256, 2) k_nu_b(
    const float* __restrict__ tmp, const float* __restrict__ w, const float* __restrict__ b,
    int N, float* __restrict__ h) {
    int n = blockIdx.x * blockDim.x + threadIdx.x;
    if (n >= N) return;
    float tv[64];
    const float4* tr = (const float4*)(tmp + (size_t)n * HID);
#pragma unroll
    for (int c = 0; c < 16; c++) {
        float4 v = tr[c];
        tv[c * 4 + 0] = v.x; tv[c * 4 + 1] = v.y; tv[c * 4 + 2] = v.z; tv[c * 4 + 3] = v.w;
    }
    float4* hr = (float4*)(h + (size_t)n * HID);
#pragma unroll 2
    for (int c = 0; c < 16; c++) {
        float4 hv = hr[c];
        float* hp = (float*)&hv;
#pragma unroll
        for (int q = 0; q < 4; q++) {
            int f = c * 4 + q;
            float acc = b[f];
#pragma unroll
            for (int j = 0; j < 64; j++) acc += tv[j] * w[f * 64 + j];
            hp[q] += acc;
        }
        hr[c] = hv;
    }
}

// ---------------- readout MLP + scatter mean accumulation ----------------
__global__ void __launch_bounds__(256, 2) k_readout(
    const float* __restrict__ h, const int* __restrict__ batch,
    const float* __restrict__ w1, const float* __restrict__ b1,
    const float* __restrict__ w2, const float* __restrict__ b2,
    int N, float* __restrict__ sums, float* __restrict__ counts) {
    int n = blockIdx.x * blockDim.x + threadIdx.x;
    if (n >= N) return;
    float hv[64];
    const float4* hr = (const float4*)(h + (size_t)n * HID);
#pragma unroll
    for (int c = 0; c < 16; c++) {
        float4 v = hr[c];
        hv[c * 4 + 0] = v.x; hv[c * 4 + 1] = v.y; hv[c * 4 + 2] = v.z; hv[c * 4 + 3] = v.w;
    }
    float o = b2[0];
#pragma unroll 2
    for (int j = 0; j < 32; j++) {
        float acc = b1[j];
#pragma unroll
        for (int k = 0; k < 64; k++) acc += hv[k] * w1[j * 64 + k];
        o += sspf(acc) * w2[j];
    }
    int b = batch[n];
    unsafeAtomicAdd(&sums[b], o);
    unsafeAtomicAdd(&counts[b], 1.0f);
}

__global__ void k_finalize(const float* __restrict__ sums, const float* __restrict__ counts,
                           int G, float* __restrict__ out) {
    int g = blockIdx.x * blockDim.x + threadIdx.x;
    if (g >= G) return;
    out[g] = sums[g] / fmaxf(counts[g], 1.0f);
}

extern "C" void kernel_launch(void* const* d_in, const int* in_sizes, int n_in,
                              void* d_out, int out_size, void* d_ws, size_t ws_size,
                              hipStream_t stream) {
    const float* pos    = (const float*)d_in[0];
    const float* shifts = (const float*)d_in[1];
    const float* attrs  = (const float*)d_in[2];
    const int*   batch  = (const int*)d_in[3];
    const int*   ei     = (const int*)d_in[4];
    const float* wv     = (const float*)d_in[5];
    const float* mlp_w1 = (const float*)d_in[6];
    const float* mlp_b1 = (const float*)d_in[7];
    const float* mlp_w2 = (const float*)d_in[8];
    const float* mlp_b2 = (const float*)d_in[9];
    const float* lin1w  = (const float*)d_in[10];
    const float* lin2w  = (const float*)d_in[11];
    const float* lin2b  = (const float*)d_in[12];
    const float* linw   = (const float*)d_in[13];
    const float* linb   = (const float*)d_in[14];
    const float* ow1    = (const float*)d_in[15];
    const float* ob1    = (const float*)d_in[16];
    const float* ow2    = (const float*)d_in[17];
    const float* ob2    = (const float*)d_in[18];

    const int N = in_sizes[0] / 3;       // 100000
    const int E = in_sizes[4] / 2;       // 1600000
    const int G = out_size;              // 1000

    char* w = (char*)d_ws;
    size_t off = 0;
    auto alloc = [&](size_t bytes) -> char* {
        char* p = w + off;
        off = (off + bytes + 255) & ~(size_t)255;
        return p;
    };
    int*    cnt       = (int*)alloc((size_t)N * 4);
    int*    row_start = (int*)alloc((size_t)(N + 1) * 4);
    int*    cursor    = (int*)alloc((size_t)N * 4);
    int*    carry     = (int*)alloc(1024 * 4);
    int*    carry_ex  = (int*)alloc(1024 * 4);
    float4* e_pack    = (float4*)alloc((size_t)E * 16);
    float*  h         = (float*)alloc((size_t)N * HID * 4);
    float*  xf        = (float*)alloc((size_t)N * FIL * 4);   // also reused as tmp in nu_a/nu_b
    float*  agg       = (float*)alloc((size_t)N * FIL * 4);
    float*  tab       = (float*)alloc((size_t)2 * TBL * FIL * 4); // 4.2 MB
    float*  sums      = (float*)alloc((size_t)G * 4);
    float*  cnts      = (float*)alloc((size_t)G * 4);
    (void)ws_size;

    const int B = 256;
    const int nblk = (N + 1023) / 1024;

    // CSR build (once per call; ws re-poisoned each call)
    hipMemsetAsync(cnt, 0, (size_t)N * 4, stream);
    k_count<<<(E + B - 1) / B, B, 0, stream>>>(ei, E, cnt);
    k_scan_blk<<<nblk, 1024, 0, stream>>>(cnt, N, row_start, carry);
    k_scan_carry<<<1, 1024, 0, stream>>>(carry, nblk, carry_ex);
    k_scan_add<<<(N + B - 1) / B, B, 0, stream>>>(row_start, carry_ex, N, E, cursor);
    k_fill<<<(E + B - 1) / B, B, 0, stream>>>(pos, shifts, ei, E, cursor, e_pack);

    // W(d) tables for both layers + embedding (embed fused with layer-0 lin1)
    k_table<<<(2 * TBL * 16 + B - 1) / B, B, 0, stream>>>(mlp_w1, mlp_b1, mlp_w2, mlp_b2, tab);
    k_embed_lin1<<<(N + B - 1) / B, B, 0, stream>>>(attrs, wv, lin1w, N, h, xf);

    for (int l = 0; l < 2; l++) {
        if (l > 0)
            k_lin1<<<(N + B - 1) / B, B, 0, stream>>>(h, lin1w + l * 4096, N, xf);
        k_edge_agg<<<((size_t)N * 64 + 255) / 256, 256, 0, stream>>>(
            e_pack, row_start, N, tab + (size_t)l * TBL * FIL, xf, agg);
        k_nu_a<<<(N + B - 1) / B, B, 0, stream>>>(agg, lin2w + l * 4096, lin2b + l * 64, N, xf);
        k_nu_b<<<(N + B - 1) / B, B, 0, stream>>>(xf, linw + l * 4096, linb + l * 64, N, h);
    }

    hipMemsetAsync(sums, 0, (size_t)G * 4, stream);
    hipMemsetAsync(cnts, 0, (size_t)G * 4, stream);
    k_readout<<<(N + B - 1) / B, B, 0, stream>>>(h, batch, ow1, ob1, ow2, ob2, N, sums, cnts);
    k_finalize<<<(G + B - 1) / B, B, 0, stream>>>(sums, cnts, G, (float*)d_out);
}